// Round 19
// baseline (212.341 us; speedup 1.0000x reference)
//
#include <hip/hip_runtime.h>

constexpr int N_NODES = 100000;
constexpr int N_EDGES = 1600000;
constexpr int DIN = 128, DHID = 256, DOUT = 128;

constexpr int NB = 256;    // buckets
constexpr int BR = 391;    // node range per bucket (256*391 = 100096 >= N)
constexpr int CAP = 8192;  // per-bucket capacity (mean 6250)
constexpr int NBLK1 = 256; // partition blocks (512 threads each)
constexpr int CHUNK = (N_EDGES + NBLK1 - 1) / NBLK1;  // 6250 (exact: 256*6250 = E)
constexpr int NIT = (CHUNK + 511) / 512;              // 13 per-thread slots

typedef __bf16 bf16x8 __attribute__((ext_vector_type(8)));
typedef float f32x4 __attribute__((ext_vector_type(4)));

static __device__ __forceinline__ ushort f2bf(float f) {
    uint u = __float_as_uint(f);
    uint r = (u + 0x7FFFu + ((u >> 16) & 1u)) >> 16;
    return (ushort)r;
}
static __device__ __forceinline__ float bf2f(ushort h) {
    return __uint_as_float(((uint)h) << 16);
}
static __device__ __forceinline__ float bflo(uint w) { return __uint_as_float(w << 16); }
static __device__ __forceinline__ float bfhi(uint w) { return __uint_as_float(w & 0xFFFF0000u); }

// ---------------- pass 1: partition edges into 256 buckets (packed records) ----------------
__global__ __launch_bounds__(512) void part_kernel(const int* __restrict__ src,
                                                   const int* __restrict__ dst,
                                                   int* __restrict__ curA, int* __restrict__ curB,
                                                   uint* __restrict__ ppair,
                                                   ushort* __restrict__ psv, int e,
                                                   const float* __restrict__ W1,
                                                   ushort* __restrict__ Wf1,
                                                   const float* __restrict__ W2,
                                                   ushort* __restrict__ Wf2) {
    const int t = threadIdx.x;
    if (blockIdx.x >= NBLK1) {  // weight fragment-layout blocks (128 x 512 = 65536)
        int i = (blockIdx.x - NBLK1) * 512 + t;
        if (i < DIN * DHID) {
            int frag = i >> 9, r = i & 511;
            int lane = r >> 3, ee = r & 7;
            int kb = frag & 3, ii = (frag >> 2) & 1, w = (frag >> 3) & 3, kh = frag >> 5;
            int c = w * 32 + ii * 16 + (lane & 15);  // W1 col within half
            int k = kb * 32 + (lane >> 4) * 8 + ee;  // W1 row (k-dim)
            Wf1[i] = f2bf(W1[k * DHID + kh * 128 + c]);
        } else {
            int i2 = i - DIN * DHID;
            int frag = i2 >> 9, r = i2 & 511;
            int lane = r >> 3, ee = r & 7;
            int kb2 = frag & 3, j2 = (frag >> 2) & 1, w = (frag >> 3) & 3, kh = frag >> 5;
            int c2 = w * 32 + j2 * 16 + (lane & 15);              // T col
            int k2 = kh * 128 + kb2 * 32 + (lane >> 4) * 8 + ee;  // k-dim in [0,256)
            Wf2[i2] = f2bf(W2[k2 * DOUT + c2]);
        }
        return;
    }
    __shared__ int hA[NB], hB[NB], rA[NB], rB[NB], cA[NB], cB[NB];  // 6 KB
    const int b0 = blockIdx.x * CHUNK;
    const int cnt = min(e - b0, CHUNK);
    if (t < NB) { hA[t] = 0; hB[t] = 0; cA[t] = 0; cB[t] = 0; }
    __syncthreads();

    int sA[NIT], dA[NIT];
#pragma unroll
    for (int i = 0; i < NIT; i++) {
        int idx = i * 512 + t;
        if (idx < cnt) {
            sA[i] = src[b0 + idx];
            dA[i] = dst[b0 + idx];
            atomicAdd(&hA[dA[i] / BR], 1);
            atomicAdd(&hB[sA[i] / BR], 1);
        }
    }
    __syncthreads();
    if (t < NB) {
        rA[t] = atomicAdd(&curA[t], hA[t]);  // global reservation
        rB[t] = atomicAdd(&curB[t], hB[t]);
    }
    __syncthreads();
#pragma unroll
    for (int i = 0; i < NIT; i++) {
        int idx = i * 512 + t;
        if (idx < cnt) {
            int s = sA[i], d = dA[i];
            int bd = d / BR;
            int bs = s / BR;
            int p = rA[bd] + atomicAdd(&cA[bd], 1);
            if (p < CAP) ppair[(size_t)bd * CAP + p] = ((uint)(d - bd * BR) << 17) | (uint)s;
            int q = rB[bs] + atomicAdd(&cB[bs], 1);
            if (q < CAP) psv[(size_t)bs * CAP + q] = (ushort)(s - bs * BR);
        }
    }
}

// ---------------- pass 2 (SPLIT): 2 blocks per bucket ----------------
__global__ __launch_bounds__(512) void csrn_kernel(const int* __restrict__ curA,
                                                   const int* __restrict__ curB,
                                                   const uint* __restrict__ ppair,
                                                   const ushort* __restrict__ psv,
                                                   int* __restrict__ csr,
                                                   int* __restrict__ rowstart,
                                                   float* __restrict__ ndst,
                                                   float* __restrict__ nsrc,
                                                   const float* __restrict__ x,
                                                   ushort* __restrict__ xb, int n, int e) {
    __shared__ uint ploc[CAP];  // 32KB (side 0 only)
    __shared__ int hist[512], sc[512], exc[512], cur[512];
    __shared__ int sbst;
    const int t = threadIdx.x;
    const int b = blockIdx.x & 255;
    const int side = blockIdx.x >> 8;
    const int first = b * BR;
    const int nr = min(BR, n - first);
    const size_t base = (size_t)b * CAP;

    if (side == 0) {
        const int cntA = min(curA[b], CAP);
        if (t < 256) sc[t] = curA[t];
        __syncthreads();
        for (int off = 1; off < 256; off <<= 1) {
            int add = 0;
            if (t < 256 && t >= off) add = sc[t - off];
            __syncthreads();
            if (t < 256) sc[t] += add;
            __syncthreads();
        }
        if (t == 0) {
            sbst = (b == 0) ? 0 : sc[b - 1];
            if (b == 0) rowstart[n] = e;
        }
        hist[t] = 0;
        cur[t] = 0;
        __syncthreads();
        const int bst = sbst;

        for (int i = t; i < cntA; i += 512) {
            uint p = ppair[base + i];
            ploc[i] = p;
            atomicAdd(&hist[p >> 17], 1);
        }
        __syncthreads();
        int h = hist[t];
        sc[t] = h;
        __syncthreads();
        for (int off = 1; off < 512; off <<= 1) {
            int add = (t >= off) ? sc[t - off] : 0;
            __syncthreads();
            sc[t] += add;
            __syncthreads();
        }
        exc[t] = sc[t] - h;
        if (t < nr) {
            rowstart[first + t] = bst + exc[t];
            ndst[first + t] = rsqrtf(fmaxf((float)h, 1.0f));
        }
        __syncthreads();
        for (int i = t; i < cntA; i += 512) {
            uint p = ploc[i];
            int dl = p >> 17;
            int pos = exc[dl] + atomicAdd(&cur[dl], 1);
            csr[bst + pos] = (int)(p & 0x1FFFFu);
        }
    } else {
        if (nr <= 0) return;
        hist[t] = 0;
        __syncthreads();
        const int cntB = min(curB[b], CAP);
        for (int i = t; i < cntB; i += 512) atomicAdd(&hist[psv[base + i]], 1);
        __syncthreads();
        float* nsv = (float*)exc;  // reuse as float nsrc cache
        if (t < nr) {
            float v = rsqrtf(fmaxf((float)hist[t], 1.0f));
            nsrc[first + t] = v;
            nsv[t] = v;
        }
        __syncthreads();
        const int rl = t >> 5, q = t & 31;
        for (int i = rl; i < nr; i += 16) {
            float s = nsv[i];
            const size_t ro = (size_t)(first + i) * 128;
            float4 v = *(const float4*)&x[ro + q * 4];
            ushort4 o = {f2bf(v.x * s), f2bf(v.y * s), f2bf(v.z * s), f2bf(v.w * s)};
            *(ushort4*)&xb[ro + q * 4] = o;
        }
    }
}

// ---------------- half-feature gather-aggregate, both halves in one dispatch ----------------
template <bool OUTBF16, bool ADDBIAS>
__global__ __launch_bounds__(256) void aggh_kernel(const ushort* __restrict__ Xb,
                                                   const int* __restrict__ csr,
                                                   const int* __restrict__ rowstart,
                                                   const float* __restrict__ ndst,
                                                   const float* __restrict__ bias,
                                                   float* __restrict__ outf,
                                                   ushort* __restrict__ outb, int n, int G) {
    const int half = blockIdx.x & 1;
    const int bid = blockIdx.x >> 1;
    int g = threadIdx.x >> 3;    // 0..31 row group
    int lane = threadIdx.x & 7;  // 8 lanes x 8 bf16 = 128 B half-row
    int d = bid * 32 + g;
    if (d >= n) return;
    int beg = rowstart[d], end = rowstart[d + 1];
    const int fo = half * 64 + lane * 8;
    const ushort* Xp = Xb + fo;
    float acc[8];
#pragma unroll
    for (int j = 0; j < 8; j++) acc[j] = 0.f;

#define ACC8(v)                                   \
    do {                                          \
        acc[0] += bflo(v.x); acc[1] += bfhi(v.x); \
        acc[2] += bflo(v.y); acc[3] += bfhi(v.y); \
        acc[4] += bflo(v.z); acc[5] += bfhi(v.z); \
        acc[6] += bflo(v.w); acc[7] += bfhi(v.w); \
    } while (0)

    int k = beg;
    for (; k + 8 <= end; k += 8) {
        int s0 = csr[k], s1 = csr[k + 1], s2 = csr[k + 2], s3 = csr[k + 3];
        int s4 = csr[k + 4], s5 = csr[k + 5], s6 = csr[k + 6], s7 = csr[k + 7];
        uint4 v0 = *(const uint4*)(Xp + (size_t)s0 * 128);
        uint4 v1 = *(const uint4*)(Xp + (size_t)s1 * 128);
        uint4 v2 = *(const uint4*)(Xp + (size_t)s2 * 128);
        uint4 v3 = *(const uint4*)(Xp + (size_t)s3 * 128);
        uint4 v4 = *(const uint4*)(Xp + (size_t)s4 * 128);
        uint4 v5 = *(const uint4*)(Xp + (size_t)s5 * 128);
        uint4 v6 = *(const uint4*)(Xp + (size_t)s6 * 128);
        uint4 v7 = *(const uint4*)(Xp + (size_t)s7 * 128);
        ACC8(v0);
        ACC8(v1);
        ACC8(v2);
        ACC8(v3);
        ACC8(v4);
        ACC8(v5);
        ACC8(v6);
        ACC8(v7);
    }
    for (; k + 4 <= end; k += 4) {
        int s0 = csr[k], s1 = csr[k + 1], s2 = csr[k + 2], s3 = csr[k + 3];
        uint4 v0 = *(const uint4*)(Xp + (size_t)s0 * 128);
        uint4 v1 = *(const uint4*)(Xp + (size_t)s1 * 128);
        uint4 v2 = *(const uint4*)(Xp + (size_t)s2 * 128);
        uint4 v3 = *(const uint4*)(Xp + (size_t)s3 * 128);
        ACC8(v0);
        ACC8(v1);
        ACC8(v2);
        ACC8(v3);
    }
    for (; k < end; ++k) {
        uint4 v = *(const uint4*)(Xp + (size_t)csr[k] * 128);
        ACC8(v);
    }
#undef ACC8

    float nd = ndst[d];
#pragma unroll
    for (int j = 0; j < 8; j++) acc[j] *= nd;
    if constexpr (ADDBIAS) {
        float4 b0 = *(const float4*)&bias[fo];
        float4 b1 = *(const float4*)&bias[fo + 4];
        acc[0] += b0.x; acc[1] += b0.y; acc[2] += b0.z; acc[3] += b0.w;
        acc[4] += b1.x; acc[5] += b1.y; acc[6] += b1.z; acc[7] += b1.w;
    }
    if constexpr (OUTBF16) {
        uint4 o;
        o.x = (uint)f2bf(acc[0]) | ((uint)f2bf(acc[1]) << 16);
        o.y = (uint)f2bf(acc[2]) | ((uint)f2bf(acc[3]) << 16);
        o.z = (uint)f2bf(acc[4]) | ((uint)f2bf(acc[5]) << 16);
        o.w = (uint)f2bf(acc[6]) | ((uint)f2bf(acc[7]) << 16);
        *(uint4*)(outb + (size_t)d * 128 + fo) = o;
    } else {
        float4 o0 = {acc[0], acc[1], acc[2], acc[3]};
        float4 o1 = {acc[4], acc[5], acc[6], acc[7]};
        *(float4*)(outf + (size_t)d * 128 + fo) = o0;
        *(float4*)(outf + (size_t)d * 128 + fo + 4) = o1;
    }
}

// ---------------- fused GEMM1+GEMM2, BM=64: A fragments DIRECT from global (no Sa LDS) -------
// Swapped-operand phase B reads 16B-contiguous per-lane A fragments straight from row-major
// A (L2-resident, 4x re-read of the 16KB tile is free). Only H1 (a true transpose) uses LDS
// -> 16 KB total, higher blocks/CU, one less barrier.
__global__ __launch_bounds__(256) void fused64_kernel(const ushort* __restrict__ A,
                                                      const ushort* __restrict__ Wf1,
                                                      const float* __restrict__ b1,
                                                      const float* __restrict__ nsrc,
                                                      const ushort* __restrict__ Wf2,
                                                      ushort* __restrict__ T, int M) {
    __shared__ ushort H1[64][128];  // H half [m][c], oct' = oct ^ (m&15)  16 KB
    const int row0 = blockIdx.x * 64;
    const int t = threadIdx.x;
    const int w = t >> 6, lane = t & 63;
    const int l16 = lane & 15, lk = lane >> 4;

    // per-lane A row bases (clamped; rows >= M only affect discarded outputs)
    const ushort* arow[4];
    float nsv[4];
#pragma unroll
    for (int j = 0; j < 4; j++) {
        int gm = row0 + j * 16 + l16;
        if (gm >= M) gm = M - 1;
        arow[j] = A + (size_t)gm * 128 + lk * 8;
        nsv[j] = nsrc[gm];
    }
    float4 bvv[2][2];
#pragma unroll
    for (int kh = 0; kh < 2; kh++)
#pragma unroll
        for (int i = 0; i < 2; i++)
            bvv[kh][i] = *(const float4*)&b1[kh * 128 + w * 32 + i * 16 + lk * 4];

    f32x4 acc2[4][2];
#pragma unroll
    for (int i = 0; i < 4; i++)
#pragma unroll
        for (int j = 0; j < 2; j++) acc2[i][j] = (f32x4){0.f, 0.f, 0.f, 0.f};

    for (int kh = 0; kh < 2; kh++) {
        // ---- all 16 weight fragment loads for this kh, coalesced 1KB each ----
        const ushort* w1p = Wf1 + ((size_t)(kh * 4 + w) * 8) * 512 + lane * 8;
        const ushort* w2p = Wf2 + ((size_t)(kh * 4 + w) * 8) * 512 + lane * 8;
        bf16x8 af[2][4], wb[2][4];
#pragma unroll
        for (int i = 0; i < 2; i++)
#pragma unroll
            for (int kb = 0; kb < 4; kb++) af[i][kb] = *(const bf16x8*)(w1p + (i * 4 + kb) * 512);
#pragma unroll
        for (int j2 = 0; j2 < 2; j2++)
#pragma unroll
            for (int kb2 = 0; kb2 < 4; kb2++)
                wb[j2][kb2] = *(const bf16x8*)(w2p + (j2 * 4 + kb2) * 512);

        // ---- phase B: acc1 = (A @ W1half)^T ; wave w owns c-rows [w*32, w*32+32) ----
        f32x4 acc1[2][4];
#pragma unroll
        for (int i = 0; i < 2; i++)
#pragma unroll
            for (int j = 0; j < 4; j++) acc1[i][j] = (f32x4){0.f, 0.f, 0.f, 0.f};

#pragma unroll
        for (int kb = 0; kb < 4; kb++) {
            bf16x8 bf_[4];
#pragma unroll
            for (int j = 0; j < 4; j++) bf_[j] = *(const bf16x8*)(arow[j] + kb * 32);
#pragma unroll
            for (int i = 0; i < 2; i++)
#pragma unroll
                for (int j = 0; j < 4; j++)
                    acc1[i][j] =
                        __builtin_amdgcn_mfma_f32_16x16x32_bf16(af[i][kb], bf_[j], acc1[i][j], 0, 0, 0);
        }
        __syncthreads();  // prior phase-D H1 reads done before overwrite

        // ---- epilogue: lane holds D[c = w*32+i*16+lk*4+q][m = j*16+l16] -> H1 ----
#pragma unroll
        for (int i = 0; i < 2; i++) {
            int cb = w * 32 + i * 16 + lk * 4;
            float4 bv = bvv[kh][i];
#pragma unroll
            for (int j = 0; j < 4; j++) {
                int m = j * 16 + l16;
                float ns = nsv[j];
                ushort4 pk;
                pk.x = f2bf(fmaxf(acc1[i][j][0] + bv.x, 0.f) * ns);
                pk.y = f2bf(fmaxf(acc1[i][j][1] + bv.y, 0.f) * ns);
                pk.z = f2bf(fmaxf(acc1[i][j][2] + bv.z, 0.f) * ns);
                pk.w = f2bf(fmaxf(acc1[i][j][3] + bv.w, 0.f) * ns);
                int oct = cb >> 3;
                *(ushort4*)((char*)&H1[0][0] + m * 256 + ((oct ^ l16) & 15) * 16 +
                            (cb & 7) * 2) = pk;
            }
        }
        __syncthreads();  // H1 visible

        // ---- phase D: acc2 += H1 @ W2half ; wave w owns T-cols [w*32, w*32+32) ----
#pragma unroll
        for (int kb2 = 0; kb2 < 4; kb2++) {
            bf16x8 ha[4];
#pragma unroll
            for (int i2 = 0; i2 < 4; i2++) {
                int m = i2 * 16 + l16;
                ha[i2] = *(const bf16x8*)((const char*)&H1[0][0] + m * 256 +
                                          ((kb2 * 4 + lk) ^ l16) * 16);
            }
#pragma unroll
            for (int i2 = 0; i2 < 4; i2++)
#pragma unroll
                for (int j2 = 0; j2 < 2; j2++)
                    acc2[i2][j2] = __builtin_amdgcn_mfma_f32_16x16x32_bf16(ha[i2], wb[j2][kb2],
                                                                           acc2[i2][j2], 0, 0, 0);
        }
    }

    // ---- write T: C/D layout col=lane&15, row=(lane>>4)*4+q ----
#pragma unroll
    for (int i2 = 0; i2 < 4; i2++) {
#pragma unroll
        for (int j2 = 0; j2 < 2; j2++) {
#pragma unroll
            for (int q = 0; q < 4; q++) {
                int r = row0 + i2 * 16 + lk * 4 + q;
                int c = w * 32 + j2 * 16 + l16;
                if (r < M) T[(size_t)r * DOUT + c] = f2bf(acc2[i2][j2][q]);
            }
        }
    }
}

extern "C" void kernel_launch(void* const* d_in, const int* in_sizes, int n_in,
                              void* d_out, int out_size, void* d_ws, size_t ws_size,
                              hipStream_t stream) {
    const float* x  = (const float*)d_in[0];
    const int*   src = (const int*)d_in[1];
    const int*   dst = (const int*)d_in[2];
    const float* W1 = (const float*)d_in[3];
    const float* b1 = (const float*)d_in[4];
    const float* W2 = (const float*)d_in[5];
    const float* b2 = (const float*)d_in[6];
    float* out = (float*)d_out;

    const int N = N_NODES, E = N_EDGES;

    size_t off = 0;
    auto carve = [&](size_t bytes) -> void* {
        void* p = (char*)d_ws + off;
        off += (bytes + 255) & ~(size_t)255;
        return p;
    };
    int* curA     = (int*)carve(NB * 4);
    int* curB     = (int*)carve(NB * 4);
    int* rowstart = (int*)carve((size_t)(N + 1) * 4);
    float* ndst   = (float*)carve((size_t)N * 4);
    float* nsrc   = (float*)carve((size_t)N * 4);
    int* csr      = (int*)carve((size_t)E * 4);
    ushort* Wf1   = (ushort*)carve(DIN * DHID * 2);        // fragment-ordered
    ushort* Wf2   = (ushort*)carve(DHID * DOUT * 2);       // fragment-ordered
    ushort* xb    = (ushort*)carve((size_t)N * DIN * 2);   // bf16(x*nsrc)
    ushort* agg1b = (ushort*)carve((size_t)N * DIN * 2);   // bf16 aggregate (fused A)
    ushort* tb    = (ushort*)carve((size_t)N * DOUT * 2);  // bf16 fused output
    uint*   ppair = (uint*)carve((size_t)NB * CAP * 4);    // packed (dl<<17 | s)  8.4 MB
    ushort* psv   = (ushort*)carve((size_t)NB * CAP * 2);  // packed local src     4.2 MB

    hipMemsetAsync(curA, 0, 2 * NB * 4, stream);

    // partition edges (256 blocks x 512 thr, register-carried) + weight fragment layout
    part_kernel<<<NBLK1 + 128, 512, 0, stream>>>(src, dst, curA, curB, ppair, psv, E,
                                                 W1, Wf1, W2, Wf2);
    // CSR+ndst (blocks 0..255) || nsrc+xb (blocks 256..511)
    csrn_kernel<<<2 * NB, 512, 0, stream>>>(curA, curB, ppair, psv, csr, rowstart, ndst, nsrc,
                                            x, xb, N, E);

    const int gagg = (N + 31) / 32;
    // layer 1 aggregation (both feature halves, XCD-parity-assigned)
    aggh_kernel<true, false><<<2 * gagg, 256, 0, stream>>>(xb, csr, rowstart, ndst, nullptr,
                                                           nullptr, agg1b, N, gagg);

    // fused GEMM1+GEMM2: tb = bf16( (relu(agg1b @ W1 + b1) * nsrc) @ W2 )
    fused64_kernel<<<(N + 63) / 64, 256, 0, stream>>>(agg1b, Wf1, b1, nsrc, Wf2, tb, N);

    // layer 2 aggregation (both halves): out = ndst * segsum(tb[src]) + b2
    aggh_kernel<false, true><<<2 * gagg, 256, 0, stream>>>(tb, csr, rowstart, ndst, b2,
                                                           out, nullptr, N, gagg);
}

// Round 20
// 196.230 us; speedup vs baseline: 1.0821x; 1.0821x over previous
//
#include <hip/hip_runtime.h>

constexpr int N_NODES = 100000;
constexpr int N_EDGES = 1600000;
constexpr int DIN = 128, DHID = 256, DOUT = 128;

constexpr int NB = 256;    // buckets
constexpr int BR = 391;    // node range per bucket (256*391 = 100096 >= N)
constexpr int CAP = 8192;  // per-bucket capacity (mean 6250)
constexpr int NBLK1 = 256; // partition blocks (512 threads each)
constexpr int CHUNK = (N_EDGES + NBLK1 - 1) / NBLK1;  // 6250 (exact: 256*6250 = E)
constexpr int NIT = (CHUNK + 511) / 512;              // 13 per-thread slots

typedef __bf16 bf16x8 __attribute__((ext_vector_type(8)));
typedef float f32x4 __attribute__((ext_vector_type(4)));

static __device__ __forceinline__ ushort f2bf(float f) {
    uint u = __float_as_uint(f);
    uint r = (u + 0x7FFFu + ((u >> 16) & 1u)) >> 16;
    return (ushort)r;
}
static __device__ __forceinline__ float bf2f(ushort h) {
    return __uint_as_float(((uint)h) << 16);
}
static __device__ __forceinline__ float bflo(uint w) { return __uint_as_float(w << 16); }
static __device__ __forceinline__ float bfhi(uint w) { return __uint_as_float(w & 0xFFFF0000u); }

// ---------------- pass 1: partition edges into 256 buckets (packed records) ----------------
// ppair entry: (dl << 17) | s ; psv entry: ushort (s - bucket*BR)
// Edges carried in REGISTERS across hist -> reserve -> scatter (single global read).
// Extra blocks (>= NBLK1) build PRE-SWIZZLED weight fragment buffers Wf1/Wf2.
__global__ __launch_bounds__(512) void part_kernel(const int* __restrict__ src,
                                                   const int* __restrict__ dst,
                                                   int* __restrict__ curA, int* __restrict__ curB,
                                                   uint* __restrict__ ppair,
                                                   ushort* __restrict__ psv, int e,
                                                   const float* __restrict__ W1,
                                                   ushort* __restrict__ Wf1,
                                                   const float* __restrict__ W2,
                                                   ushort* __restrict__ Wf2) {
    const int t = threadIdx.x;
    if (blockIdx.x >= NBLK1) {  // weight fragment-layout blocks (128 x 512 = 65536)
        int i = (blockIdx.x - NBLK1) * 512 + t;
        if (i < DIN * DHID) {
            int frag = i >> 9, r = i & 511;
            int lane = r >> 3, ee = r & 7;
            int kb = frag & 3, ii = (frag >> 2) & 1, w = (frag >> 3) & 3, kh = frag >> 5;
            int c = w * 32 + ii * 16 + (lane & 15);  // W1 col within half
            int k = kb * 32 + (lane >> 4) * 8 + ee;  // W1 row (k-dim)
            Wf1[i] = f2bf(W1[k * DHID + kh * 128 + c]);
        } else {
            int i2 = i - DIN * DHID;
            int frag = i2 >> 9, r = i2 & 511;
            int lane = r >> 3, ee = r & 7;
            int kb2 = frag & 3, j2 = (frag >> 2) & 1, w = (frag >> 3) & 3, kh = frag >> 5;
            int c2 = w * 32 + j2 * 16 + (lane & 15);              // T col
            int k2 = kh * 128 + kb2 * 32 + (lane >> 4) * 8 + ee;  // k-dim in [0,256)
            Wf2[i2] = f2bf(W2[k2 * DOUT + c2]);
        }
        return;
    }
    __shared__ int hA[NB], hB[NB], rA[NB], rB[NB], cA[NB], cB[NB];  // 6 KB
    const int b0 = blockIdx.x * CHUNK;
    const int cnt = min(e - b0, CHUNK);
    if (t < NB) { hA[t] = 0; hB[t] = 0; cA[t] = 0; cB[t] = 0; }
    __syncthreads();

    int sA[NIT], dA[NIT];
#pragma unroll
    for (int i = 0; i < NIT; i++) {
        int idx = i * 512 + t;
        if (idx < cnt) {
            sA[i] = src[b0 + idx];
            dA[i] = dst[b0 + idx];
            atomicAdd(&hA[dA[i] / BR], 1);
            atomicAdd(&hB[sA[i] / BR], 1);
        }
    }
    __syncthreads();
    if (t < NB) {
        rA[t] = atomicAdd(&curA[t], hA[t]);  // global reservation
        rB[t] = atomicAdd(&curB[t], hB[t]);
    }
    __syncthreads();
#pragma unroll
    for (int i = 0; i < NIT; i++) {
        int idx = i * 512 + t;
        if (idx < cnt) {
            int s = sA[i], d = dA[i];
            int bd = d / BR;
            int bs = s / BR;
            int p = rA[bd] + atomicAdd(&cA[bd], 1);
            if (p < CAP) ppair[(size_t)bd * CAP + p] = ((uint)(d - bd * BR) << 17) | (uint)s;
            int q = rB[bs] + atomicAdd(&cB[bs], 1);
            if (q < CAP) psv[(size_t)bs * CAP + q] = (ushort)(s - bs * BR);
        }
    }
}

// ---------------- pass 2 (SPLIT): 2 blocks per bucket ----------------
// blocks 0..255    (side 0): per-bucket CSR build + rowstart + ndst   (consumes ppair)
// blocks 256..511  (side 1): per-bucket nsrc + xb = bf16(x*nsrc)      (consumes psv, x)
__global__ __launch_bounds__(512) void csrn_kernel(const int* __restrict__ curA,
                                                   const int* __restrict__ curB,
                                                   const uint* __restrict__ ppair,
                                                   const ushort* __restrict__ psv,
                                                   int* __restrict__ csr,
                                                   int* __restrict__ rowstart,
                                                   float* __restrict__ ndst,
                                                   float* __restrict__ nsrc,
                                                   const float* __restrict__ x,
                                                   ushort* __restrict__ xb, int n, int e) {
    __shared__ uint ploc[CAP];  // 32KB (side 0 only)
    __shared__ int hist[512], sc[512], exc[512], cur[512];
    __shared__ int sbst;
    const int t = threadIdx.x;
    const int b = blockIdx.x & 255;
    const int side = blockIdx.x >> 8;
    const int first = b * BR;
    const int nr = min(BR, n - first);
    const size_t base = (size_t)b * CAP;

    if (side == 0) {
        const int cntA = min(curA[b], CAP);
        if (t < 256) sc[t] = curA[t];
        __syncthreads();
        for (int off = 1; off < 256; off <<= 1) {
            int add = 0;
            if (t < 256 && t >= off) add = sc[t - off];
            __syncthreads();
            if (t < 256) sc[t] += add;
            __syncthreads();
        }
        if (t == 0) {
            sbst = (b == 0) ? 0 : sc[b - 1];
            if (b == 0) rowstart[n] = e;
        }
        hist[t] = 0;
        cur[t] = 0;
        __syncthreads();
        const int bst = sbst;

        for (int i = t; i < cntA; i += 512) {
            uint p = ppair[base + i];
            ploc[i] = p;
            atomicAdd(&hist[p >> 17], 1);
        }
        __syncthreads();
        int h = hist[t];
        sc[t] = h;
        __syncthreads();
        for (int off = 1; off < 512; off <<= 1) {
            int add = (t >= off) ? sc[t - off] : 0;
            __syncthreads();
            sc[t] += add;
            __syncthreads();
        }
        exc[t] = sc[t] - h;
        if (t < nr) {
            rowstart[first + t] = bst + exc[t];
            ndst[first + t] = rsqrtf(fmaxf((float)h, 1.0f));
        }
        __syncthreads();
        for (int i = t; i < cntA; i += 512) {
            uint p = ploc[i];
            int dl = p >> 17;
            int pos = exc[dl] + atomicAdd(&cur[dl], 1);
            csr[bst + pos] = (int)(p & 0x1FFFFu);
        }
    } else {
        if (nr <= 0) return;
        hist[t] = 0;
        __syncthreads();
        const int cntB = min(curB[b], CAP);
        for (int i = t; i < cntB; i += 512) atomicAdd(&hist[psv[base + i]], 1);
        __syncthreads();
        float* nsv = (float*)exc;  // reuse as float nsrc cache
        if (t < nr) {
            float v = rsqrtf(fmaxf((float)hist[t], 1.0f));
            nsrc[first + t] = v;
            nsv[t] = v;
        }
        __syncthreads();
        const int rl = t >> 5, q = t & 31;
        for (int i = rl; i < nr; i += 16) {
            float s = nsv[i];
            const size_t ro = (size_t)(first + i) * 128;
            float4 v = *(const float4*)&x[ro + q * 4];
            ushort4 o = {f2bf(v.x * s), f2bf(v.y * s), f2bf(v.z * s), f2bf(v.w * s)};
            *(ushort4*)&xb[ro + q * 4] = o;
        }
    }
}

// ---------------- half-feature gather-aggregate, both halves in one dispatch ----------------
// half = blockIdx & 1 (XCD-parity assignment); 32 rows/block, 8 lanes x 16B per row;
// 8-edge unroll (k-ascending order unchanged).
template <bool OUTBF16, bool ADDBIAS>
__global__ __launch_bounds__(256) void aggh_kernel(const ushort* __restrict__ Xb,
                                                   const int* __restrict__ csr,
                                                   const int* __restrict__ rowstart,
                                                   const float* __restrict__ ndst,
                                                   const float* __restrict__ bias,
                                                   float* __restrict__ outf,
                                                   ushort* __restrict__ outb, int n, int G) {
    const int half = blockIdx.x & 1;
    const int bid = blockIdx.x >> 1;
    int g = threadIdx.x >> 3;    // 0..31 row group
    int lane = threadIdx.x & 7;  // 8 lanes x 8 bf16 = 128 B half-row
    int d = bid * 32 + g;
    if (d >= n) return;
    int beg = rowstart[d], end = rowstart[d + 1];
    const int fo = half * 64 + lane * 8;
    const ushort* Xp = Xb + fo;
    float acc[8];
#pragma unroll
    for (int j = 0; j < 8; j++) acc[j] = 0.f;

#define ACC8(v)                                   \
    do {                                          \
        acc[0] += bflo(v.x); acc[1] += bfhi(v.x); \
        acc[2] += bflo(v.y); acc[3] += bfhi(v.y); \
        acc[4] += bflo(v.z); acc[5] += bfhi(v.z); \
        acc[6] += bflo(v.w); acc[7] += bfhi(v.w); \
    } while (0)

    int k = beg;
    for (; k + 8 <= end; k += 8) {
        int s0 = csr[k], s1 = csr[k + 1], s2 = csr[k + 2], s3 = csr[k + 3];
        int s4 = csr[k + 4], s5 = csr[k + 5], s6 = csr[k + 6], s7 = csr[k + 7];
        uint4 v0 = *(const uint4*)(Xp + (size_t)s0 * 128);
        uint4 v1 = *(const uint4*)(Xp + (size_t)s1 * 128);
        uint4 v2 = *(const uint4*)(Xp + (size_t)s2 * 128);
        uint4 v3 = *(const uint4*)(Xp + (size_t)s3 * 128);
        uint4 v4 = *(const uint4*)(Xp + (size_t)s4 * 128);
        uint4 v5 = *(const uint4*)(Xp + (size_t)s5 * 128);
        uint4 v6 = *(const uint4*)(Xp + (size_t)s6 * 128);
        uint4 v7 = *(const uint4*)(Xp + (size_t)s7 * 128);
        ACC8(v0);
        ACC8(v1);
        ACC8(v2);
        ACC8(v3);
        ACC8(v4);
        ACC8(v5);
        ACC8(v6);
        ACC8(v7);
    }
    for (; k + 4 <= end; k += 4) {
        int s0 = csr[k], s1 = csr[k + 1], s2 = csr[k + 2], s3 = csr[k + 3];
        uint4 v0 = *(const uint4*)(Xp + (size_t)s0 * 128);
        uint4 v1 = *(const uint4*)(Xp + (size_t)s1 * 128);
        uint4 v2 = *(const uint4*)(Xp + (size_t)s2 * 128);
        uint4 v3 = *(const uint4*)(Xp + (size_t)s3 * 128);
        ACC8(v0);
        ACC8(v1);
        ACC8(v2);
        ACC8(v3);
    }
    for (; k < end; ++k) {
        uint4 v = *(const uint4*)(Xp + (size_t)csr[k] * 128);
        ACC8(v);
    }
#undef ACC8

    float nd = ndst[d];
#pragma unroll
    for (int j = 0; j < 8; j++) acc[j] *= nd;
    if constexpr (ADDBIAS) {
        float4 b0 = *(const float4*)&bias[fo];
        float4 b1 = *(const float4*)&bias[fo + 4];
        acc[0] += b0.x; acc[1] += b0.y; acc[2] += b0.z; acc[3] += b0.w;
        acc[4] += b1.x; acc[5] += b1.y; acc[6] += b1.z; acc[7] += b1.w;
    }
    if constexpr (OUTBF16) {
        uint4 o;
        o.x = (uint)f2bf(acc[0]) | ((uint)f2bf(acc[1]) << 16);
        o.y = (uint)f2bf(acc[2]) | ((uint)f2bf(acc[3]) << 16);
        o.z = (uint)f2bf(acc[4]) | ((uint)f2bf(acc[5]) << 16);
        o.w = (uint)f2bf(acc[6]) | ((uint)f2bf(acc[7]) << 16);
        *(uint4*)(outb + (size_t)d * 128 + fo) = o;
    } else {
        float4 o0 = {acc[0], acc[1], acc[2], acc[3]};
        float4 o1 = {acc[4], acc[5], acc[6], acc[7]};
        *(float4*)(outf + (size_t)d * 128 + fo) = o0;
        *(float4*)(outf + (size_t)d * 128 + fo + 4) = o1;
    }
}

// ---------------- fused GEMM1+GEMM2, BM=64, pre-swizzled weight fragments ----------------
__global__ __launch_bounds__(256) void fused64_kernel(const ushort* __restrict__ A,
                                                      const ushort* __restrict__ Wf1,
                                                      const float* __restrict__ b1,
                                                      const float* __restrict__ nsrc,
                                                      const ushort* __restrict__ Wf2,
                                                      ushort* __restrict__ T, int M) {
    __shared__ ushort Sa[64][128];  // A tile [m][k], oct' = oct ^ (m&15)   16 KB
    __shared__ ushort H1[64][128];  // H half [m][c], same swizzle          16 KB
    const int row0 = blockIdx.x * 64;
    const int t = threadIdx.x;
    const int w = t >> 6, lane = t & 63;
    const int l16 = lane & 15, lk = lane >> 4;

    // prefetch per-lane nsrc + biases (tiny, before barrier)
    float nsv[4];
#pragma unroll
    for (int j = 0; j < 4; j++) {
        int gm = row0 + j * 16 + l16;
        nsv[j] = nsrc[gm < M ? gm : (M - 1)];
    }
    float4 bvv[2][2];
#pragma unroll
    for (int kh = 0; kh < 2; kh++)
#pragma unroll
        for (int i = 0; i < 2; i++)
            bvv[kh][i] = *(const float4*)&b1[kh * 128 + w * 32 + i * 16 + lk * 4];

    // stage A tile once (64 rows x 128 k)
#pragma unroll
    for (int i = 0; i < 4; i++) {
        int idx = i * 256 + t;  // 1024 uint4 pieces
        int r = idx >> 4, oct = idx & 15;
        int gr = row0 + r;
        uint4 v = make_uint4(0u, 0u, 0u, 0u);
        if (gr < M) v = *(const uint4*)&A[(size_t)gr * 128 + oct * 8];
        *(uint4*)((char*)&Sa[0][0] + r * 256 + (oct ^ (r & 15)) * 16) = v;
    }
    __syncthreads();

    f32x4 acc2[4][2];
#pragma unroll
    for (int i = 0; i < 4; i++)
#pragma unroll
        for (int j = 0; j < 2; j++) acc2[i][j] = (f32x4){0.f, 0.f, 0.f, 0.f};

    for (int kh = 0; kh < 2; kh++) {
        // ---- all 16 weight fragment loads for this kh, coalesced 1KB each ----
        const ushort* w1p = Wf1 + ((size_t)(kh * 4 + w) * 8) * 512 + lane * 8;
        const ushort* w2p = Wf2 + ((size_t)(kh * 4 + w) * 8) * 512 + lane * 8;
        bf16x8 af[2][4], wb[2][4];
#pragma unroll
        for (int i = 0; i < 2; i++)
#pragma unroll
            for (int kb = 0; kb < 4; kb++) af[i][kb] = *(const bf16x8*)(w1p + (i * 4 + kb) * 512);
#pragma unroll
        for (int j2 = 0; j2 < 2; j2++)
#pragma unroll
            for (int kb2 = 0; kb2 < 4; kb2++)
                wb[j2][kb2] = *(const bf16x8*)(w2p + (j2 * 4 + kb2) * 512);

        // ---- phase B: acc1 = (A @ W1half)^T ; wave w owns c-rows [w*32, w*32+32) ----
        f32x4 acc1[2][4];
#pragma unroll
        for (int i = 0; i < 2; i++)
#pragma unroll
            for (int j = 0; j < 4; j++) acc1[i][j] = (f32x4){0.f, 0.f, 0.f, 0.f};

#pragma unroll
        for (int kb = 0; kb < 4; kb++) {
            bf16x8 bf_[4];
#pragma unroll
            for (int j = 0; j < 4; j++) {
                int m = j * 16 + l16;
                bf_[j] = *(const bf16x8*)((const char*)&Sa[0][0] + m * 256 +
                                          ((kb * 4 + lk) ^ l16) * 16);
            }
#pragma unroll
            for (int i = 0; i < 2; i++)
#pragma unroll
                for (int j = 0; j < 4; j++)
                    acc1[i][j] =
                        __builtin_amdgcn_mfma_f32_16x16x32_bf16(af[i][kb], bf_[j], acc1[i][j], 0, 0, 0);
        }
        __syncthreads();  // prior phase-D H1 reads done before overwrite

        // ---- epilogue: lane holds D[c = w*32+i*16+lk*4+q][m = j*16+l16] -> H1 ----
#pragma unroll
        for (int i = 0; i < 2; i++) {
            int cb = w * 32 + i * 16 + lk * 4;
            float4 bv = bvv[kh][i];
#pragma unroll
            for (int j = 0; j < 4; j++) {
                int m = j * 16 + l16;
                float ns = nsv[j];
                ushort4 pk;
                pk.x = f2bf(fmaxf(acc1[i][j][0] + bv.x, 0.f) * ns);
                pk.y = f2bf(fmaxf(acc1[i][j][1] + bv.y, 0.f) * ns);
                pk.z = f2bf(fmaxf(acc1[i][j][2] + bv.z, 0.f) * ns);
                pk.w = f2bf(fmaxf(acc1[i][j][3] + bv.w, 0.f) * ns);
                int oct = cb >> 3;
                *(ushort4*)((char*)&H1[0][0] + m * 256 + ((oct ^ l16) & 15) * 16 +
                            (cb & 7) * 2) = pk;
            }
        }
        __syncthreads();  // H1 visible

        // ---- phase D: acc2 += H1 @ W2half ; wave w owns T-cols [w*32, w*32+32) ----
#pragma unroll
        for (int kb2 = 0; kb2 < 4; kb2++) {
            bf16x8 ha[4];
#pragma unroll
            for (int i2 = 0; i2 < 4; i2++) {
                int m = i2 * 16 + l16;
                ha[i2] = *(const bf16x8*)((const char*)&H1[0][0] + m * 256 +
                                          ((kb2 * 4 + lk) ^ l16) * 16);
            }
#pragma unroll
            for (int i2 = 0; i2 < 4; i2++)
#pragma unroll
                for (int j2 = 0; j2 < 2; j2++)
                    acc2[i2][j2] = __builtin_amdgcn_mfma_f32_16x16x32_bf16(ha[i2], wb[j2][kb2],
                                                                           acc2[i2][j2], 0, 0, 0);
        }
    }

    // ---- write T: C/D layout col=lane&15, row=(lane>>4)*4+q ----
#pragma unroll
    for (int i2 = 0; i2 < 4; i2++) {
#pragma unroll
        for (int j2 = 0; j2 < 2; j2++) {
#pragma unroll
            for (int q = 0; q < 4; q++) {
                int r = row0 + i2 * 16 + lk * 4 + q;
                int c = w * 32 + j2 * 16 + l16;
                if (r < M) T[(size_t)r * DOUT + c] = f2bf(acc2[i2][j2][q]);
            }
        }
    }
}

extern "C" void kernel_launch(void* const* d_in, const int* in_sizes, int n_in,
                              void* d_out, int out_size, void* d_ws, size_t ws_size,
                              hipStream_t stream) {
    const float* x  = (const float*)d_in[0];
    const int*   src = (const int*)d_in[1];
    const int*   dst = (const int*)d_in[2];
    const float* W1 = (const float*)d_in[3];
    const float* b1 = (const float*)d_in[4];
    const float* W2 = (const float*)d_in[5];
    const float* b2 = (const float*)d_in[6];
    float* out = (float*)d_out;

    const int N = N_NODES, E = N_EDGES;

    size_t off = 0;
    auto carve = [&](size_t bytes) -> void* {
        void* p = (char*)d_ws + off;
        off += (bytes + 255) & ~(size_t)255;
        return p;
    };
    int* curA     = (int*)carve(NB * 4);
    int* curB     = (int*)carve(NB * 4);
    int* rowstart = (int*)carve((size_t)(N + 1) * 4);
    float* ndst   = (float*)carve((size_t)N * 4);
    float* nsrc   = (float*)carve((size_t)N * 4);
    int* csr      = (int*)carve((size_t)E * 4);
    ushort* Wf1   = (ushort*)carve(DIN * DHID * 2);        // fragment-ordered
    ushort* Wf2   = (ushort*)carve(DHID * DOUT * 2);       // fragment-ordered
    ushort* xb    = (ushort*)carve((size_t)N * DIN * 2);   // bf16(x*nsrc)
    ushort* agg1b = (ushort*)carve((size_t)N * DIN * 2);   // bf16 aggregate (fused A)
    ushort* tb    = (ushort*)carve((size_t)N * DOUT * 2);  // bf16 fused output
    uint*   ppair = (uint*)carve((size_t)NB * CAP * 4);    // packed (dl<<17 | s)  8.4 MB
    ushort* psv   = (ushort*)carve((size_t)NB * CAP * 2);  // packed local src     4.2 MB

    hipMemsetAsync(curA, 0, 2 * NB * 4, stream);

    // partition edges (256 blocks x 512 thr, register-carried) + weight fragment layout
    part_kernel<<<NBLK1 + 128, 512, 0, stream>>>(src, dst, curA, curB, ppair, psv, E,
                                                 W1, Wf1, W2, Wf2);
    // CSR+ndst (blocks 0..255) || nsrc+xb (blocks 256..511)
    csrn_kernel<<<2 * NB, 512, 0, stream>>>(curA, curB, ppair, psv, csr, rowstart, ndst, nsrc,
                                            x, xb, N, E);

    const int gagg = (N + 31) / 32;
    // layer 1 aggregation (both feature halves, XCD-parity-assigned)
    aggh_kernel<true, false><<<2 * gagg, 256, 0, stream>>>(xb, csr, rowstart, ndst, nullptr,
                                                           nullptr, agg1b, N, gagg);

    // fused GEMM1+GEMM2: tb = bf16( (relu(agg1b @ W1 + b1) * nsrc) @ W2 )
    fused64_kernel<<<(N + 63) / 64, 256, 0, stream>>>(agg1b, Wf1, b1, nsrc, Wf2, tb, N);

    // layer 2 aggregation (both halves): out = ndst * segsum(tb[src]) + b2
    aggh_kernel<false, true><<<2 * gagg, 256, 0, stream>>>(tb, csr, rowstart, ndst, b2,
                                                           out, nullptr, N, gagg);
}